// Round 12
// baseline (803.392 us; speedup 1.0000x reference)
//
#include <hip/hip_runtime.h>
#include <math.h>

#define N_NODES 20000
#define N_EDGES 320000

typedef __attribute__((ext_vector_type(8))) short bf16x8;
typedef __attribute__((ext_vector_type(4))) float f32x4;
typedef unsigned short ushort_t;
typedef unsigned int uint_t;

__device__ __forceinline__ float bf2f(uint_t u) {
    uint_t i = u << 16; float f; __builtin_memcpy(&f, &i, 4); return f;
}
__device__ __forceinline__ ushort_t f2bf(float f) {
    uint_t i; __builtin_memcpy(&i, &f, 4);
    uint_t r = i + 0x7fffu + ((i >> 16) & 1u);
    return (ushort_t)(r >> 16);
}

// ---------------------------------------------------------------------------
// Pack weights into MFMA fragment order, bf16:
// layout per weight: [k0 = K/32][ot = NO/16][lane = 64][8 bf16]
// lane's 8 elems = W[row = ot*16 + (lane&15)][k = k0*32 + (lane>>4)*8 + j]
// job 0 = WPQ (P/Q transform of enc_w1); job 8 = [muw;lvw]; job 9 = biases
// ---------------------------------------------------------------------------
__global__ void pack_all(const float* __restrict__ w1, const float* __restrict__ b1,
                         const float* __restrict__ w2,
                         const float* __restrict__ hiw0, const float* __restrict__ hiw1,
                         const float* __restrict__ wih0, const float* __restrict__ whh0,
                         const float* __restrict__ wih1, const float* __restrict__ whh1,
                         const float* __restrict__ muw, const float* __restrict__ lvw,
                         const float* __restrict__ mub, const float* __restrict__ lvb,
                         ushort_t* __restrict__ pk, float* __restrict__ bpq)
{
    const int w = blockIdx.y;
    const int i = blockIdx.x * 256 + threadIdx.x;
    if (w == 9) {
        if (i < 256)      bpq[i] = b1[i];
        else if (i < 512) bpq[i] = 0.0f;
        else if (i < 576) bpq[i] = mub[i - 512];
        else if (i < 640) bpq[i] = lvb[i - 576];
        return;
    }
    const int Ks[9]  = {128, 256, 288, 288, 288, 256, 256, 256, 256};
    const int NOs[9] = {512, 256, 256, 256, 768, 768, 768, 768, 128};
    const int DST[9] = {0, 65536, 131072, 204800, 278528, 499712, 696320, 892928, 1089536};
    const float* srcs[9] = {w1, w2, hiw0, hiw1, wih0, whh0, wih1, whh1, muw};
    const int K = Ks[w], NO = NOs[w];
    if (i >= (K * NO) >> 3) return;
    const int lane = i & 63, rest = i >> 6, NOT = NO >> 4;
    const int ot = rest % NOT, k0 = rest / NOT;
    const int row = ot * 16 + (lane & 15);
    const int kb = k0 * 32 + (lane >> 4) * 8;
    ushort_t o[8];
    if (w == 0) {
#pragma unroll
        for (int j = 0; j < 8; ++j) {
            int k = kb + j;
            float v = (row < 256) ? (w1[row * 256 + k] - w1[row * 256 + 128 + k])
                                  : w1[(row - 256) * 256 + 128 + k];
            o[j] = f2bf(v);
        }
    } else if (w == 8) {
#pragma unroll
        for (int j = 0; j < 8; ++j) {
            float v = (row < 64) ? muw[row * 256 + kb + j] : lvw[(row - 64) * 256 + kb + j];
            o[j] = f2bf(v);
        }
    } else {
        const float* s = srcs[w];
#pragma unroll
        for (int j = 0; j < 8; ++j) o[j] = f2bf(s[(size_t)row * K + kb + j]);
    }
    ushort_t* d = pk + DST[w] + (size_t)i * 8;
    ((uint_t*)d)[0] = (uint_t)o[0] | ((uint_t)o[1] << 16);
    ((uint_t*)d)[1] = (uint_t)o[2] | ((uint_t)o[3] << 16);
    ((uint_t*)d)[2] = (uint_t)o[4] | ((uint_t)o[5] << 16);
    ((uint_t*)d)[3] = (uint_t)o[6] | ((uint_t)o[7] << 16);
}

// x f32 -> bf16
__global__ void xcvt(const float* __restrict__ x, ushort_t* __restrict__ xbf)
{
    int base = (blockIdx.x * 256 + threadIdx.x) * 4;
    if (base >= N_NODES * 128) return;
    float4 v = *(const float4*)&x[base];
    uint2 u;
    u.x = (uint_t)f2bf(v.x) | ((uint_t)f2bf(v.y) << 16);
    u.y = (uint_t)f2bf(v.z) | ((uint_t)f2bf(v.w) << 16);
    *(uint2*)&xbf[base] = u;
}

// ---------------------------------------------------------------------------
// MFMA GEMM: C = act(Abf[M,K] @ W^T + bias).  BM=64, BN in {64,128},
// 256 thr / 4 waves.  A staged in LDS (XOR swizzle (row&7)<<4).
// OMODE: 0=f32, 1=bf16, 2=dual f32+bf16 with tanh,
//        4=fused heads: BN=128, cols 0-63 mu / 64-127 lv of SAME output col;
//          writes mu, lv, z (=mu+eps*exp(0.5*lv)); Cbf is (const float*)eps.
// ---------------------------------------------------------------------------
template <int BN, int OMODE>
__global__ __launch_bounds__(256) void mgemm(
    const ushort_t* __restrict__ Abf, int lda, int M, int K,
    const ushort_t* __restrict__ Wp, int NOtot, const float* __restrict__ bias,
    float* __restrict__ Cf, ushort_t* __restrict__ Cbf, int ldc)
{
    __shared__ char smem[40960];
    const int tid = threadIdx.x;
    const int l = tid & 63, wid = tid >> 6;
    const int m0 = blockIdx.x * 64;
    const int n0 = blockIdx.y * BN;
    const int RS = (K * 2 + 127) & ~127;
    const int CHR = K >> 3;
    for (int c = tid; c < 64 * CHR; c += 256) {
        int row = c / CHR, cb = c - row * CHR;
        int gr = m0 + row; if (gr >= M) gr = M - 1;
        bf16x8 v = *(const bf16x8*)&Abf[(size_t)gr * lda + cb * 8];
        *(bf16x8*)&smem[row * RS + ((cb * 16) ^ ((row & 7) << 4))] = v;
    }
    __syncthreads();

    constexpr int NT = BN / 16;
    f32x4 acc[NT];
#pragma unroll
    for (int j = 0; j < NT; ++j) acc[j] = (f32x4){0.f, 0.f, 0.f, 0.f};
    const int rw = wid * 16 + (l & 15);
    const int hi = l >> 4;
    const int swz = (rw & 7) << 4;
    const int KB = K >> 5;
    const int otb = n0 >> 4;
    for (int k0 = 0; k0 < KB; ++k0) {
        bf16x8 a = *(const bf16x8*)&smem[rw * RS + ((k0 * 64 + hi * 16) ^ swz)];
        const ushort_t* wb = Wp + ((size_t)(k0 * NOtot + otb) * 64 + l) * 8;
#pragma unroll
        for (int j = 0; j < NT; ++j) {
            bf16x8 b = *(const bf16x8*)&wb[(size_t)j * 512];
            acc[j] = __builtin_amdgcn_mfma_f32_16x16x32_bf16(a, b, acc[j], 0, 0, 0);
        }
    }
    const int c0 = l & 15;
    const int r0 = m0 + wid * 16 + hi * 4;
    if (OMODE == 4) {
        const float* epsp = (const float*)Cbf;
#pragma unroll
        for (int j = 0; j < 4; ++j) {
            int c = j * 16 + c0;
            float bmu = bias[c], blv = bias[64 + c];
#pragma unroll
            for (int r = 0; r < 4; ++r) {
                int gr = r0 + r;
                if (gr >= M) continue;
                float mu = acc[j][r] + bmu;
                float lv = acc[j + 4][r] + blv;
                float e  = epsp[(size_t)gr * 64 + c];
                Cf[(size_t)gr * 64 + c] = mu;
                Cf[(size_t)M * 64 + (size_t)gr * 64 + c] = lv;
                Cf[(size_t)2 * M * 64 + (size_t)gr * 64 + c] = mu + e * expf(0.5f * lv);
            }
        }
        return;
    }
#pragma unroll
    for (int j = 0; j < NT; ++j) {
        float bj = bias[n0 + j * 16 + c0];
#pragma unroll
        for (int r = 0; r < 4; ++r) {
            int gr = r0 + r;
            if (gr >= M) continue;
            float v = acc[j][r] + bj;
            if (OMODE == 2) v = tanhf(v);
            size_t o = (size_t)gr * ldc + n0 + j * 16 + c0;
            if (OMODE == 0) Cf[o] = v;
            else if (OMODE == 1) Cbf[o] = f2bf(v);
            else { Cf[o] = v; Cbf[o] = f2bf(v); }
        }
    }
}

// ---------------------------------------------------------------------------
// Edge kernel: 32 edges/block.  MFMA layer-2: wave = 16 edges x 128 cols.
// Segment-max: pre-read agg and only atomicMax when beating the current
// value (agg monotonic >=0, stale reads only under-read -> safe).  Cuts
// memory-side atomic traffic ~4.7x (E[deg=16 updates] ~ H(16)=3.4).
// ---------------------------------------------------------------------------
__global__ __launch_bounds__(256) void edge_mfma(
    const ushort_t* __restrict__ PQbf,
    const int* __restrict__ ei,
    const ushort_t* __restrict__ W2p,
    const float* __restrict__ b2,
    float* __restrict__ agg)
{
    __shared__ char h1s[16384];           // 32 x 512B
    __shared__ int s_dst[32], s_src[32];
    const int tid = threadIdx.x;
    const int e0 = blockIdx.x * 32;
    if (tid < 32) {
        int d = ei[N_EDGES + e0 + tid];
        s_dst[tid] = min(max(d, 0), N_NODES - 1);
    } else if (tid < 64) {
        int s = ei[e0 + tid - 32];
        s_src[tid - 32] = min(max(s, 0), N_NODES - 1);
    }
    __syncthreads();

    const int wv = tid >> 6;       // wave id: edges wv, wv+4, ...
    const int ln = tid & 63;       // lane: channels ln*4 .. ln*4+3
#pragma unroll 4
    for (int eb = wv; eb < 32; eb += 4) {
        int dst = s_dst[eb], src = s_src[eb];
        uint2 pu = *(const uint2*)&PQbf[(size_t)dst * 512 + ln * 4];
        uint2 qu = *(const uint2*)&PQbf[(size_t)src * 512 + 256 + ln * 4];
        float v0 = fmaxf(bf2f(pu.x & 0xffffu) + bf2f(qu.x & 0xffffu), 0.f);
        float v1 = fmaxf(bf2f(pu.x >> 16)     + bf2f(qu.x >> 16),     0.f);
        float v2 = fmaxf(bf2f(pu.y & 0xffffu) + bf2f(qu.y & 0xffffu), 0.f);
        float v3 = fmaxf(bf2f(pu.y >> 16)     + bf2f(qu.y >> 16),     0.f);
        uint2 hv;
        hv.x = (uint_t)f2bf(v0) | ((uint_t)f2bf(v1) << 16);
        hv.y = (uint_t)f2bf(v2) | ((uint_t)f2bf(v3) << 16);
        *(uint2*)&h1s[eb * 512 + ((ln * 8) ^ ((eb & 7) << 4))] = hv;
    }
    __syncthreads();

    // wave -> (row-tile, col-half): rows (wid&1)*16..+15, cols (wid>>1)*128..+127
    const int l = tid & 63, wid = tid >> 6;
    const int rw = (wid & 1) * 16 + (l & 15);
    const int hi = l >> 4;
    const int swz = (rw & 7) << 4;
    const int otb = (wid >> 1) * 8;       // first 16-col tile index of this wave
    f32x4 acc[8];
#pragma unroll
    for (int j = 0; j < 8; ++j) acc[j] = (f32x4){0.f, 0.f, 0.f, 0.f};
    for (int k0 = 0; k0 < 8; ++k0) {
        bf16x8 a = *(const bf16x8*)&h1s[rw * 512 + ((k0 * 64 + hi * 16) ^ swz)];
        const ushort_t* wb = W2p + ((size_t)(k0 * 16 + otb) * 64 + l) * 8;
#pragma unroll
        for (int j = 0; j < 8; ++j) {
            bf16x8 b = *(const bf16x8*)&wb[(size_t)j * 512];
            acc[j] = __builtin_amdgcn_mfma_f32_16x16x32_bf16(a, b, acc[j], 0, 0, 0);
        }
    }
    const int c0 = l & 15;
    const int edg = (wid & 1) * 16 + hi * 4;
#pragma unroll
    for (int j = 0; j < 8; ++j) {
        int col = (otb + j) * 16 + c0;
        float bj = b2[col];
#pragma unroll
        for (int r = 0; r < 4; ++r) {
            float v = acc[j][r] + bj;
            if (v > 0.f) {
                int node = s_dst[edg + r];
                int* addr = (int*)&agg[(size_t)node * 256 + col];
                int iv = __float_as_int(v);
                if (iv > *addr) atomicMax(addr, iv);   // int cmp == float cmp for >=0
            }
        }
    }
}

// feat[N,288] = [agg | t | a] -> bf16
__global__ void build_feat(const float* __restrict__ agg, const float* __restrict__ t,
                           const float* __restrict__ a, ushort_t* __restrict__ featbf)
{
    int idx = blockIdx.x * 256 + threadIdx.x;
    if (idx >= N_NODES * 288) return;
    int n = idx / 288, c = idx - n * 288;
    float v;
    if (c < 256)      v = agg[(size_t)n * 256 + c];
    else if (c < 272) v = t[n * 16 + (c - 256)];
    else              v = a[n * 16 + (c - 272)];
    featbf[idx] = f2bf(v);
}

// ---------------------------------------------------------------------------
// Fused GRU layer: gi = A1 @ wih^T, gh = A2 @ whh^T, then full GRU combine.
// Block = 64 rows x 64 gate-channels. Wp layout identical to mgemm packing
// with NOtot=48 (gates stacked r|z|n in the 768-row dimension).
// ---------------------------------------------------------------------------
__global__ __launch_bounds__(256) void gru_fused(
    const ushort_t* __restrict__ A1, int K1,
    const ushort_t* __restrict__ A2,              // [N,256]
    const ushort_t* __restrict__ Wp1,
    const ushort_t* __restrict__ Wp2,
    const float* __restrict__ bih, const float* __restrict__ bhh,
    const float* __restrict__ hf,                 // [N,256] f32
    float* __restrict__ houtf,
    ushort_t* __restrict__ houtb)
{
    __shared__ char smem[40960];
    const int tid = threadIdx.x;
    const int l = tid & 63, wid = tid >> 6;
    const int m0 = blockIdx.x * 64;
    const int n0 = blockIdx.y * 64;
    const int rw = wid * 16 + (l & 15);
    const int hi = l >> 4;
    const int swz = (rw & 7) << 4;
    const int otb = n0 >> 4;

    f32x4 aR[4], aZ[4], aN[4], bR[4], bZ[4], bN[4];
#pragma unroll
    for (int j = 0; j < 4; ++j) {
        aR[j] = (f32x4){0.f,0.f,0.f,0.f}; aZ[j] = aR[j]; aN[j] = aR[j];
        bR[j] = aR[j]; bZ[j] = aR[j]; bN[j] = aR[j];
    }

    // ---- stage A1, K-loop 1 (input gates)
    {
        const int RS = (K1 * 2 + 127) & ~127;
        const int CHR = K1 >> 3;
        for (int c = tid; c < 64 * CHR; c += 256) {
            int row = c / CHR, cb = c - row * CHR;
            int gr = m0 + row; if (gr >= N_NODES) gr = N_NODES - 1;
            bf16x8 v = *(const bf16x8*)&A1[(size_t)gr * K1 + cb * 8];
            *(bf16x8*)&smem[row * RS + ((cb * 16) ^ ((row & 7) << 4))] = v;
        }
        __syncthreads();
        const int KB = K1 >> 5;
        for (int k0 = 0; k0 < KB; ++k0) {
            bf16x8 a = *(const bf16x8*)&smem[rw * RS + ((k0 * 64 + hi * 16) ^ swz)];
            const ushort_t* wb = Wp1 + ((size_t)(k0 * 48) * 64 + l) * 8;
#pragma unroll
            for (int j = 0; j < 4; ++j) {
                bf16x8 b0 = *(const bf16x8*)&wb[(size_t)(otb + j) * 512];
                aR[j] = __builtin_amdgcn_mfma_f32_16x16x32_bf16(a, b0, aR[j], 0, 0, 0);
                bf16x8 b1 = *(const bf16x8*)&wb[(size_t)(16 + otb + j) * 512];
                aZ[j] = __builtin_amdgcn_mfma_f32_16x16x32_bf16(a, b1, aZ[j], 0, 0, 0);
                bf16x8 b2 = *(const bf16x8*)&wb[(size_t)(32 + otb + j) * 512];
                aN[j] = __builtin_amdgcn_mfma_f32_16x16x32_bf16(a, b2, aN[j], 0, 0, 0);
            }
        }
    }
    __syncthreads();
    // ---- stage A2 (K=256), K-loop 2 (hidden gates)
    {
        for (int c = tid; c < 64 * 32; c += 256) {
            int row = c >> 5, cb = c & 31;
            int gr = m0 + row; if (gr >= N_NODES) gr = N_NODES - 1;
            bf16x8 v = *(const bf16x8*)&A2[(size_t)gr * 256 + cb * 8];
            *(bf16x8*)&smem[row * 512 + ((cb * 16) ^ ((row & 7) << 4))] = v;
        }
        __syncthreads();
        for (int k0 = 0; k0 < 8; ++k0) {
            bf16x8 a = *(const bf16x8*)&smem[rw * 512 + ((k0 * 64 + hi * 16) ^ swz)];
            const ushort_t* wb = Wp2 + ((size_t)(k0 * 48) * 64 + l) * 8;
#pragma unroll
            for (int j = 0; j < 4; ++j) {
                bf16x8 b0 = *(const bf16x8*)&wb[(size_t)(otb + j) * 512];
                bR[j] = __builtin_amdgcn_mfma_f32_16x16x32_bf16(a, b0, bR[j], 0, 0, 0);
                bf16x8 b1 = *(const bf16x8*)&wb[(size_t)(16 + otb + j) * 512];
                bZ[j] = __builtin_amdgcn_mfma_f32_16x16x32_bf16(a, b1, bZ[j], 0, 0, 0);
                bf16x8 b2 = *(const bf16x8*)&wb[(size_t)(32 + otb + j) * 512];
                bN[j] = __builtin_amdgcn_mfma_f32_16x16x32_bf16(a, b2, bN[j], 0, 0, 0);
            }
        }
    }
    // ---- GRU combine epilogue
    const int c0 = l & 15;
    const int r0 = m0 + wid * 16 + hi * 4;
#pragma unroll
    for (int j = 0; j < 4; ++j) {
        int col = n0 + j * 16 + c0;
        float br_ = bih[col], bz_ = bih[256 + col], bn_ = bih[512 + col];
        float cr_ = bhh[col], cz_ = bhh[256 + col], cn_ = bhh[512 + col];
#pragma unroll
        for (int r = 0; r < 4; ++r) {
            int gr = r0 + r;
            if (gr >= N_NODES) continue;
            float ir = aR[j][r] + br_, iz = aZ[j][r] + bz_, in_ = aN[j][r] + bn_;
            float hr = bR[j][r] + cr_, hz = bZ[j][r] + cz_, hn = bN[j][r] + cn_;
            float h = hf[(size_t)gr * 256 + col];
            float rg = 1.f / (1.f + expf(-(ir + hr)));
            float zg = 1.f / (1.f + expf(-(iz + hz)));
            float ng = tanhf(in_ + rg * hn);
            float v = (1.f - zg) * ng + zg * h;
            houtf[(size_t)gr * 256 + col] = v;
            houtb[(size_t)gr * 256 + col] = f2bf(v);
        }
    }
}

extern "C" void kernel_launch(void* const* d_in, const int* in_sizes, int n_in,
                              void* d_out, int out_size, void* d_ws, size_t ws_size,
                              hipStream_t stream)
{
    const float* x      = (const float*)d_in[0];
    const float* t      = (const float*)d_in[1];
    const float* a      = (const float*)d_in[2];
    const float* eps    = (const float*)d_in[3];
    const int*   ei     = (const int*)d_in[4];
    const float* enc_w1 = (const float*)d_in[5];
    const float* enc_b1 = (const float*)d_in[6];
    const float* enc_w2 = (const float*)d_in[7];
    const float* enc_b2 = (const float*)d_in[8];
    const float* hi_w0  = (const float*)d_in[9];
    const float* hi_b0  = (const float*)d_in[10];
    const float* hi_w1  = (const float*)d_in[11];
    const float* hi_b1  = (const float*)d_in[12];
    const float* wih0   = (const float*)d_in[13];
    const float* whh0   = (const float*)d_in[14];
    const float* bih0   = (const float*)d_in[15];
    const float* bhh0   = (const float*)d_in[16];
    const float* wih1   = (const float*)d_in[17];
    const float* whh1   = (const float*)d_in[18];
    const float* bih1   = (const float*)d_in[19];
    const float* bhh1   = (const float*)d_in[20];
    const float* mu_w   = (const float*)d_in[21];
    const float* mu_b   = (const float*)d_in[22];
    const float* lv_w   = (const float*)d_in[23];
    const float* lv_b   = (const float*)d_in[24];

    // workspace layout (bytes), peak ~100.8 MB
    char* W = (char*)d_ws;
    ushort_t* pk     = (ushort_t*)(W + 0);           // 2,244,608 B packed weights
    float*    bpq    = (float*)(W + 2244608);        // 640 floats (bPQ | headbias)
    ushort_t* xbf    = (ushort_t*)(W + 2247680);     // 5,120,000
    float*    agg    = (float*)(W + 7368704);        // 20,480,000 (-> h0f)
    float*    h0f    = (float*)(W + 7368704);
    ushort_t* pqbf   = (ushort_t*)(W + 27848704);    // 20,480,000 (-> h1f)
    float*    h1f    = (float*)(W + 27848704);
    ushort_t* featbf = (ushort_t*)(W + 48328704);    // 11,520,000
    ushort_t* h0bf   = (ushort_t*)(W + 59848704);    // 10,240,000
    ushort_t* h1bf   = (ushort_t*)(W + 70088704);    // 10,240,000
    ushort_t* nh0bf  = (ushort_t*)(W + 80328704);    // 10,240,000
    ushort_t* nh1bf  = (ushort_t*)(W + 90568704);    // 10,240,000

    float* out_h0 = (float*)d_out;
    float* out_h1 = out_h0 + (size_t)N_NODES * 256;
    float* out_mu = out_h1 + (size_t)N_NODES * 256;

    dim3 blk(256);

    pack_all<<<dim3(108, 10), blk, 0, stream>>>(enc_w1, enc_b1, enc_w2, hi_w0, hi_w1,
                                                wih0, whh0, wih1, whh1, mu_w, lv_w,
                                                mu_b, lv_b, pk, bpq);
    xcvt<<<2500, blk, 0, stream>>>(x, xbf);
    hipMemsetAsync(agg, 0, (size_t)N_NODES * 256 * sizeof(float), stream);

    // PQ = xbf @ WPQ^T + bPQ -> bf16 [N,512]
    mgemm<128, 1><<<dim3(313, 4), blk, 0, stream>>>(xbf, 128, N_NODES, 128,
                                                    pk + 0, 32, bpq, nullptr, pqbf, 512);
    // edge layer2 + segment-max: 32 edges/block, 10000 blocks
    edge_mfma<<<10000, blk, 0, stream>>>(pqbf, ei, pk + 65536, enc_b2, agg);

    build_feat<<<22500, blk, 0, stream>>>(agg, t, a, featbf);

    // h0, h1 = tanh(feat @ hi_w^T + b)  (dual f32 + bf16)
    mgemm<128, 2><<<dim3(313, 2), blk, 0, stream>>>(featbf, 288, N_NODES, 288,
                                                    pk + 131072, 16, hi_b0, h0f, h0bf, 256);
    mgemm<128, 2><<<dim3(313, 2), blk, 0, stream>>>(featbf, 288, N_NODES, 288,
                                                    pk + 204800, 16, hi_b1, h1f, h1bf, 256);
    // fused GRU layers
    gru_fused<<<dim3(313, 4), blk, 0, stream>>>(featbf, 288, h0bf,
                                                pk + 278528, pk + 499712,
                                                bih0, bhh0, h0f, out_h0, nh0bf);
    gru_fused<<<dim3(313, 4), blk, 0, stream>>>(nh0bf, 256, h1bf,
                                                pk + 696320, pk + 892928,
                                                bih1, bhh1, h1f, out_h1, nh1bf);
    // fused heads: mu | lv | z in one kernel (eps via spare pointer arg)
    mgemm<128, 4><<<dim3(313, 1), blk, 0, stream>>>(nh1bf, 256, N_NODES, 256,
                                                    pk + 1089536, 8, bpq + 512,
                                                    out_mu, (ushort_t*)eps, 64);
}

// Round 13
// 742.470 us; speedup vs baseline: 1.0821x; 1.0821x over previous
//
#include <hip/hip_runtime.h>
#include <math.h>

#define N_NODES 20000
#define N_EDGES 320000

typedef __attribute__((ext_vector_type(8))) short bf16x8;
typedef __attribute__((ext_vector_type(4))) float f32x4;
typedef unsigned short ushort_t;
typedef unsigned int uint_t;

__device__ __forceinline__ float bf2f(uint_t u) {
    uint_t i = u << 16; float f; __builtin_memcpy(&f, &i, 4); return f;
}
__device__ __forceinline__ ushort_t f2bf(float f) {
    uint_t i; __builtin_memcpy(&i, &f, 4);
    uint_t r = i + 0x7fffu + ((i >> 16) & 1u);
    return (ushort_t)(r >> 16);
}

// ---------------------------------------------------------------------------
// Pack weights into MFMA fragment order, bf16 (unchanged).
// ---------------------------------------------------------------------------
__global__ void pack_all(const float* __restrict__ w1, const float* __restrict__ b1,
                         const float* __restrict__ w2,
                         const float* __restrict__ hiw0, const float* __restrict__ hiw1,
                         const float* __restrict__ wih0, const float* __restrict__ whh0,
                         const float* __restrict__ wih1, const float* __restrict__ whh1,
                         const float* __restrict__ muw, const float* __restrict__ lvw,
                         const float* __restrict__ mub, const float* __restrict__ lvb,
                         ushort_t* __restrict__ pk, float* __restrict__ bpq)
{
    const int w = blockIdx.y;
    const int i = blockIdx.x * 256 + threadIdx.x;
    if (w == 9) {
        if (i < 256)      bpq[i] = b1[i];
        else if (i < 512) bpq[i] = 0.0f;
        else if (i < 576) bpq[i] = mub[i - 512];
        else if (i < 640) bpq[i] = lvb[i - 576];
        return;
    }
    const int Ks[9]  = {128, 256, 288, 288, 288, 256, 256, 256, 256};
    const int NOs[9] = {512, 256, 256, 256, 768, 768, 768, 768, 128};
    const int DST[9] = {0, 65536, 131072, 204800, 278528, 499712, 696320, 892928, 1089536};
    const float* srcs[9] = {w1, w2, hiw0, hiw1, wih0, whh0, wih1, whh1, muw};
    const int K = Ks[w], NO = NOs[w];
    if (i >= (K * NO) >> 3) return;
    const int lane = i & 63, rest = i >> 6, NOT = NO >> 4;
    const int ot = rest % NOT, k0 = rest / NOT;
    const int row = ot * 16 + (lane & 15);
    const int kb = k0 * 32 + (lane >> 4) * 8;
    ushort_t o[8];
    if (w == 0) {
#pragma unroll
        for (int j = 0; j < 8; ++j) {
            int k = kb + j;
            float v = (row < 256) ? (w1[row * 256 + k] - w1[row * 256 + 128 + k])
                                  : w1[(row - 256) * 256 + 128 + k];
            o[j] = f2bf(v);
        }
    } else if (w == 8) {
#pragma unroll
        for (int j = 0; j < 8; ++j) {
            float v = (row < 64) ? muw[row * 256 + kb + j] : lvw[(row - 64) * 256 + kb + j];
            o[j] = f2bf(v);
        }
    } else {
        const float* s = srcs[w];
#pragma unroll
        for (int j = 0; j < 8; ++j) o[j] = f2bf(s[(size_t)row * K + kb + j]);
    }
    ushort_t* d = pk + DST[w] + (size_t)i * 8;
    ((uint_t*)d)[0] = (uint_t)o[0] | ((uint_t)o[1] << 16);
    ((uint_t*)d)[1] = (uint_t)o[2] | ((uint_t)o[3] << 16);
    ((uint_t*)d)[2] = (uint_t)o[4] | ((uint_t)o[5] << 16);
    ((uint_t*)d)[3] = (uint_t)o[6] | ((uint_t)o[7] << 16);
}

// x f32 -> bf16
__global__ void xcvt(const float* __restrict__ x, ushort_t* __restrict__ xbf)
{
    int base = (blockIdx.x * 256 + threadIdx.x) * 4;
    if (base >= N_NODES * 128) return;
    float4 v = *(const float4*)&x[base];
    uint2 u;
    u.x = (uint_t)f2bf(v.x) | ((uint_t)f2bf(v.y) << 16);
    u.y = (uint_t)f2bf(v.z) | ((uint_t)f2bf(v.w) << 16);
    *(uint2*)&xbf[base] = u;
}

// ---------------------------------------------------------------------------
// Counting sort of edges by dst: histogram -> single-block scan -> scatter.
// Order within a dst segment is arbitrary (max is order-invariant).
// ---------------------------------------------------------------------------
__global__ void hist_dst(const int* __restrict__ ei, int* __restrict__ cnt)
{
    int idx = blockIdx.x * 256 + threadIdx.x;
    if (idx >= N_EDGES) return;
    int d = ei[N_EDGES + idx];
    d = min(max(d, 0), N_NODES - 1);
    atomicAdd(&cnt[d], 1);
}

__global__ void scan_hist(const int* __restrict__ cnt, int* __restrict__ rcur)
{
    __shared__ int part[256];
    const int tidx = threadIdx.x;
    const int beg = tidx * 79;
    const int end = min(beg + 79, N_NODES);
    int s = 0;
    for (int i = beg; i < end; ++i) s += cnt[i];
    part[tidx] = s;
    __syncthreads();
    for (int off = 1; off < 256; off <<= 1) {
        int v = (tidx >= off) ? part[tidx - off] : 0;
        __syncthreads();
        part[tidx] += v;
        __syncthreads();
    }
    int run = part[tidx] - s;          // exclusive prefix for this chunk
    for (int i = beg; i < end; ++i) { int c = cnt[i]; rcur[i] = run; run += c; }
}

__global__ void scatter_edges(const int* __restrict__ ei, int* __restrict__ rcur,
                              int* __restrict__ ssrc, int* __restrict__ sdst)
{
    int idx = blockIdx.x * 256 + threadIdx.x;
    if (idx >= N_EDGES) return;
    int d = ei[N_EDGES + idx]; d = min(max(d, 0), N_NODES - 1);
    int s = ei[idx];           s = min(max(s, 0), N_NODES - 1);
    int pos = atomicAdd(&rcur[d], 1);
    sdst[pos] = d; ssrc[pos] = s;
}

// ---------------------------------------------------------------------------
// MFMA GEMM (unchanged).  OMODE: 0=f32, 1=bf16, 2=dual+tanh,
//  4=fused heads: BN=128, cols 0-63 mu / 64-127 lv; writes mu, lv, z;
//    Cbf carries (const float*)eps.
// ---------------------------------------------------------------------------
template <int BN, int OMODE>
__global__ __launch_bounds__(256) void mgemm(
    const ushort_t* __restrict__ Abf, int lda, int M, int K,
    const ushort_t* __restrict__ Wp, int NOtot, const float* __restrict__ bias,
    float* __restrict__ Cf, ushort_t* __restrict__ Cbf, int ldc)
{
    __shared__ char smem[40960];
    const int tid = threadIdx.x;
    const int l = tid & 63, wid = tid >> 6;
    const int m0 = blockIdx.x * 64;
    const int n0 = blockIdx.y * BN;
    const int RS = (K * 2 + 127) & ~127;
    const int CHR = K >> 3;
    for (int c = tid; c < 64 * CHR; c += 256) {
        int row = c / CHR, cb = c - row * CHR;
        int gr = m0 + row; if (gr >= M) gr = M - 1;
        bf16x8 v = *(const bf16x8*)&Abf[(size_t)gr * lda + cb * 8];
        *(bf16x8*)&smem[row * RS + ((cb * 16) ^ ((row & 7) << 4))] = v;
    }
    __syncthreads();

    constexpr int NT = BN / 16;
    f32x4 acc[NT];
#pragma unroll
    for (int j = 0; j < NT; ++j) acc[j] = (f32x4){0.f, 0.f, 0.f, 0.f};
    const int rw = wid * 16 + (l & 15);
    const int hi = l >> 4;
    const int swz = (rw & 7) << 4;
    const int KB = K >> 5;
    const int otb = n0 >> 4;
    for (int k0 = 0; k0 < KB; ++k0) {
        bf16x8 a = *(const bf16x8*)&smem[rw * RS + ((k0 * 64 + hi * 16) ^ swz)];
        const ushort_t* wb = Wp + ((size_t)(k0 * NOtot + otb) * 64 + l) * 8;
#pragma unroll
        for (int j = 0; j < NT; ++j) {
            bf16x8 b = *(const bf16x8*)&wb[(size_t)j * 512];
            acc[j] = __builtin_amdgcn_mfma_f32_16x16x32_bf16(a, b, acc[j], 0, 0, 0);
        }
    }
    const int c0 = l & 15;
    const int r0 = m0 + wid * 16 + hi * 4;
    if (OMODE == 4) {
        const float* epsp = (const float*)Cbf;
#pragma unroll
        for (int j = 0; j < 4; ++j) {
            int c = j * 16 + c0;
            float bmu = bias[c], blv = bias[64 + c];
#pragma unroll
            for (int r = 0; r < 4; ++r) {
                int gr = r0 + r;
                if (gr >= M) continue;
                float mu = acc[j][r] + bmu;
                float lv = acc[j + 4][r] + blv;
                float e  = epsp[(size_t)gr * 64 + c];
                Cf[(size_t)gr * 64 + c] = mu;
                Cf[(size_t)M * 64 + (size_t)gr * 64 + c] = lv;
                Cf[(size_t)2 * M * 64 + (size_t)gr * 64 + c] = mu + e * expf(0.5f * lv);
            }
        }
        return;
    }
#pragma unroll
    for (int j = 0; j < NT; ++j) {
        float bj = bias[n0 + j * 16 + c0];
#pragma unroll
        for (int r = 0; r < 4; ++r) {
            int gr = r0 + r;
            if (gr >= M) continue;
            float v = acc[j][r] + bj;
            if (OMODE == 2) v = tanhf(v);
            size_t o = (size_t)gr * ldc + n0 + j * 16 + c0;
            if (OMODE == 0) Cf[o] = v;
            else if (OMODE == 1) Cbf[o] = f2bf(v);
            else { Cf[o] = v; Cbf[o] = f2bf(v); }
        }
    }
}

// ---------------------------------------------------------------------------
// Edge kernel on dst-SORTED edges: 32 edges/block.
// P-gather now hits cache (consecutive edges share dst).  Segment-max:
// fire-and-forget atomics (round-12 pre-read regressed: agg lines don't
// stay L2-resident under cross-XCD atomics), but run-compressed over each
// lane's 4 consecutive sorted rows (~4x fewer atomics, zero added reads).
// ---------------------------------------------------------------------------
__global__ __launch_bounds__(256) void edge_mfma(
    const ushort_t* __restrict__ PQbf,
    const int* __restrict__ sdst,
    const int* __restrict__ ssrc,
    const ushort_t* __restrict__ W2p,
    const float* __restrict__ b2,
    float* __restrict__ agg)
{
    __shared__ char h1s[16384];           // 32 x 512B
    __shared__ int s_dst[32], s_src[32];
    const int tid = threadIdx.x;
    const int e0 = blockIdx.x * 32;
    if (tid < 32)       s_dst[tid] = sdst[e0 + tid];
    else if (tid < 64)  s_src[tid - 32] = ssrc[e0 + tid - 32];
    __syncthreads();

    const int wv = tid >> 6;       // wave id: edges wv, wv+4, ...
    const int ln = tid & 63;       // lane: channels ln*4 .. ln*4+3
#pragma unroll 4
    for (int eb = wv; eb < 32; eb += 4) {
        int dst = s_dst[eb], src = s_src[eb];
        uint2 pu = *(const uint2*)&PQbf[(size_t)dst * 512 + ln * 4];
        uint2 qu = *(const uint2*)&PQbf[(size_t)src * 512 + 256 + ln * 4];
        float v0 = fmaxf(bf2f(pu.x & 0xffffu) + bf2f(qu.x & 0xffffu), 0.f);
        float v1 = fmaxf(bf2f(pu.x >> 16)     + bf2f(qu.x >> 16),     0.f);
        float v2 = fmaxf(bf2f(pu.y & 0xffffu) + bf2f(qu.y & 0xffffu), 0.f);
        float v3 = fmaxf(bf2f(pu.y >> 16)     + bf2f(qu.y >> 16),     0.f);
        uint2 hv;
        hv.x = (uint_t)f2bf(v0) | ((uint_t)f2bf(v1) << 16);
        hv.y = (uint_t)f2bf(v2) | ((uint_t)f2bf(v3) << 16);
        *(uint2*)&h1s[eb * 512 + ((ln * 8) ^ ((eb & 7) << 4))] = hv;
    }
    __syncthreads();

    // wave -> (row-tile, col-half): rows (wid&1)*16..+15, cols (wid>>1)*128..+127
    const int l = tid & 63, wid = tid >> 6;
    const int rw = (wid & 1) * 16 + (l & 15);
    const int hi = l >> 4;
    const int swz = (rw & 7) << 4;
    const int otb = (wid >> 1) * 8;       // first 16-col tile index of this wave
    f32x4 acc[8];
#pragma unroll
    for (int j = 0; j < 8; ++j) acc[j] = (f32x4){0.f, 0.f, 0.f, 0.f};
    for (int k0 = 0; k0 < 8; ++k0) {
        bf16x8 a = *(const bf16x8*)&h1s[rw * 512 + ((k0 * 64 + hi * 16) ^ swz)];
        const ushort_t* wb = W2p + ((size_t)(k0 * 16 + otb) * 64 + l) * 8;
#pragma unroll
        for (int j = 0; j < 8; ++j) {
            bf16x8 b = *(const bf16x8*)&wb[(size_t)j * 512];
            acc[j] = __builtin_amdgcn_mfma_f32_16x16x32_bf16(a, b, acc[j], 0, 0, 0);
        }
    }
    const int c0 = l & 15;
    const int edg = (wid & 1) * 16 + hi * 4;   // rows = consecutive sorted edges
#pragma unroll
    for (int j = 0; j < 8; ++j) {
        int col = (otb + j) * 16 + c0;
        float bj = b2[col];
        int nd = s_dst[edg];
        float mx = 0.0f;
#pragma unroll
        for (int r = 0; r < 4; ++r) {
            float v = acc[j][r] + bj;
            int d2 = s_dst[edg + r];
            if (d2 != nd) {
                if (mx > 0.f)
                    atomicMax((int*)&agg[(size_t)nd * 256 + col], __float_as_int(mx));
                nd = d2; mx = 0.0f;
            }
            mx = fmaxf(mx, v);
        }
        if (mx > 0.f)
            atomicMax((int*)&agg[(size_t)nd * 256 + col], __float_as_int(mx));
    }
}

// feat[N,288] = [agg | t | a] -> bf16
__global__ void build_feat(const float* __restrict__ agg, const float* __restrict__ t,
                           const float* __restrict__ a, ushort_t* __restrict__ featbf)
{
    int idx = blockIdx.x * 256 + threadIdx.x;
    if (idx >= N_NODES * 288) return;
    int n = idx / 288, c = idx - n * 288;
    float v;
    if (c < 256)      v = agg[(size_t)n * 256 + c];
    else if (c < 272) v = t[n * 16 + (c - 256)];
    else              v = a[n * 16 + (c - 272)];
    featbf[idx] = f2bf(v);
}

// ---------------------------------------------------------------------------
// Fused GRU layer (unchanged).
// ---------------------------------------------------------------------------
__global__ __launch_bounds__(256) void gru_fused(
    const ushort_t* __restrict__ A1, int K1,
    const ushort_t* __restrict__ A2,
    const ushort_t* __restrict__ Wp1,
    const ushort_t* __restrict__ Wp2,
    const float* __restrict__ bih, const float* __restrict__ bhh,
    const float* __restrict__ hf,
    float* __restrict__ houtf,
    ushort_t* __restrict__ houtb)
{
    __shared__ char smem[40960];
    const int tid = threadIdx.x;
    const int l = tid & 63, wid = tid >> 6;
    const int m0 = blockIdx.x * 64;
    const int n0 = blockIdx.y * 64;
    const int rw = wid * 16 + (l & 15);
    const int hi = l >> 4;
    const int swz = (rw & 7) << 4;
    const int otb = n0 >> 4;

    f32x4 aR[4], aZ[4], aN[4], bR[4], bZ[4], bN[4];
#pragma unroll
    for (int j = 0; j < 4; ++j) {
        aR[j] = (f32x4){0.f,0.f,0.f,0.f}; aZ[j] = aR[j]; aN[j] = aR[j];
        bR[j] = aR[j]; bZ[j] = aR[j]; bN[j] = aR[j];
    }

    {
        const int RS = (K1 * 2 + 127) & ~127;
        const int CHR = K1 >> 3;
        for (int c = tid; c < 64 * CHR; c += 256) {
            int row = c / CHR, cb = c - row * CHR;
            int gr = m0 + row; if (gr >= N_NODES) gr = N_NODES - 1;
            bf16x8 v = *(const bf16x8*)&A1[(size_t)gr * K1 + cb * 8];
            *(bf16x8*)&smem[row * RS + ((cb * 16) ^ ((row & 7) << 4))] = v;
        }
        __syncthreads();
        const int KB = K1 >> 5;
        for (int k0 = 0; k0 < KB; ++k0) {
            bf16x8 a = *(const bf16x8*)&smem[rw * RS + ((k0 * 64 + hi * 16) ^ swz)];
            const ushort_t* wb = Wp1 + ((size_t)(k0 * 48) * 64 + l) * 8;
#pragma unroll
            for (int j = 0; j < 4; ++j) {
                bf16x8 b0 = *(const bf16x8*)&wb[(size_t)(otb + j) * 512];
                aR[j] = __builtin_amdgcn_mfma_f32_16x16x32_bf16(a, b0, aR[j], 0, 0, 0);
                bf16x8 b1 = *(const bf16x8*)&wb[(size_t)(16 + otb + j) * 512];
                aZ[j] = __builtin_amdgcn_mfma_f32_16x16x32_bf16(a, b1, aZ[j], 0, 0, 0);
                bf16x8 b2 = *(const bf16x8*)&wb[(size_t)(32 + otb + j) * 512];
                aN[j] = __builtin_amdgcn_mfma_f32_16x16x32_bf16(a, b2, aN[j], 0, 0, 0);
            }
        }
    }
    __syncthreads();
    {
        for (int c = tid; c < 64 * 32; c += 256) {
            int row = c >> 5, cb = c & 31;
            int gr = m0 + row; if (gr >= N_NODES) gr = N_NODES - 1;
            bf16x8 v = *(const bf16x8*)&A2[(size_t)gr * 256 + cb * 8];
            *(bf16x8*)&smem[row * 512 + ((cb * 16) ^ ((row & 7) << 4))] = v;
        }
        __syncthreads();
        for (int k0 = 0; k0 < 8; ++k0) {
            bf16x8 a = *(const bf16x8*)&smem[rw * 512 + ((k0 * 64 + hi * 16) ^ swz)];
            const ushort_t* wb = Wp2 + ((size_t)(k0 * 48) * 64 + l) * 8;
#pragma unroll
            for (int j = 0; j < 4; ++j) {
                bf16x8 b0 = *(const bf16x8*)&wb[(size_t)(otb + j) * 512];
                bR[j] = __builtin_amdgcn_mfma_f32_16x16x32_bf16(a, b0, bR[j], 0, 0, 0);
                bf16x8 b1 = *(const bf16x8*)&wb[(size_t)(16 + otb + j) * 512];
                bZ[j] = __builtin_amdgcn_mfma_f32_16x16x32_bf16(a, b1, bZ[j], 0, 0, 0);
                bf16x8 b2 = *(const bf16x8*)&wb[(size_t)(32 + otb + j) * 512];
                bN[j] = __builtin_amdgcn_mfma_f32_16x16x32_bf16(a, b2, bN[j], 0, 0, 0);
            }
        }
    }
    const int c0 = l & 15;
    const int r0 = m0 + wid * 16 + hi * 4;
#pragma unroll
    for (int j = 0; j < 4; ++j) {
        int col = n0 + j * 16 + c0;
        float br_ = bih[col], bz_ = bih[256 + col], bn_ = bih[512 + col];
        float cr_ = bhh[col], cz_ = bhh[256 + col], cn_ = bhh[512 + col];
#pragma unroll
        for (int r = 0; r < 4; ++r) {
            int gr = r0 + r;
            if (gr >= N_NODES) continue;
            float ir = aR[j][r] + br_, iz = aZ[j][r] + bz_, in_ = aN[j][r] + bn_;
            float hr = bR[j][r] + cr_, hz = bZ[j][r] + cz_, hn = bN[j][r] + cn_;
            float h = hf[(size_t)gr * 256 + col];
            float rg = 1.f / (1.f + expf(-(ir + hr)));
            float zg = 1.f / (1.f + expf(-(iz + hz)));
            float ng = tanhf(in_ + rg * hn);
            float v = (1.f - zg) * ng + zg * h;
            houtf[(size_t)gr * 256 + col] = v;
            houtb[(size_t)gr * 256 + col] = f2bf(v);
        }
    }
}

extern "C" void kernel_launch(void* const* d_in, const int* in_sizes, int n_in,
                              void* d_out, int out_size, void* d_ws, size_t ws_size,
                              hipStream_t stream)
{
    const float* x      = (const float*)d_in[0];
    const float* t      = (const float*)d_in[1];
    const float* a      = (const float*)d_in[2];
    const float* eps    = (const float*)d_in[3];
    const int*   ei     = (const int*)d_in[4];
    const float* enc_w1 = (const float*)d_in[5];
    const float* enc_b1 = (const float*)d_in[6];
    const float* enc_w2 = (const float*)d_in[7];
    const float* enc_b2 = (const float*)d_in[8];
    const float* hi_w0  = (const float*)d_in[9];
    const float* hi_b0  = (const float*)d_in[10];
    const float* hi_w1  = (const float*)d_in[11];
    const float* hi_b1  = (const float*)d_in[12];
    const float* wih0   = (const float*)d_in[13];
    const float* whh0   = (const float*)d_in[14];
    const float* bih0   = (const float*)d_in[15];
    const float* bhh0   = (const float*)d_in[16];
    const float* wih1   = (const float*)d_in[17];
    const float* whh1   = (const float*)d_in[18];
    const float* bih1   = (const float*)d_in[19];
    const float* bhh1   = (const float*)d_in[20];
    const float* mu_w   = (const float*)d_in[21];
    const float* mu_b   = (const float*)d_in[22];
    const float* lv_w   = (const float*)d_in[23];
    const float* lv_b   = (const float*)d_in[24];

    // workspace layout (bytes), peak ~103.5 MB
    char* W = (char*)d_ws;
    ushort_t* pk     = (ushort_t*)(W + 0);           // 2,244,608 B packed weights
    float*    bpq    = (float*)(W + 2244608);        // 640 floats
    ushort_t* xbf    = (ushort_t*)(W + 2247680);     // 5,120,000
    float*    agg    = (float*)(W + 7368704);        // 20,480,000 (-> h0f)
    float*    h0f    = (float*)(W + 7368704);
    ushort_t* pqbf   = (ushort_t*)(W + 27848704);    // 20,480,000 (-> h1f)
    float*    h1f    = (float*)(W + 27848704);
    ushort_t* featbf = (ushort_t*)(W + 48328704);    // 11,520,000
    ushort_t* h0bf   = (ushort_t*)(W + 59848704);    // 10,240,000
    ushort_t* h1bf   = (ushort_t*)(W + 70088704);    // 10,240,000
    ushort_t* nh0bf  = (ushort_t*)(W + 80328704);    // 10,240,000
    ushort_t* nh1bf  = (ushort_t*)(W + 90568704);    // 10,240,000
    int*      cnt    = (int*)(W + 100808704);        //     80,000
    int*      rcur   = (int*)(W + 100888704);        //     80,000
    int*      sdst   = (int*)(W + 100968704);        //  1,280,000
    int*      ssrc   = (int*)(W + 102248704);        //  1,280,000

    float* out_h0 = (float*)d_out;
    float* out_h1 = out_h0 + (size_t)N_NODES * 256;
    float* out_mu = out_h1 + (size_t)N_NODES * 256;

    dim3 blk(256);

    pack_all<<<dim3(108, 10), blk, 0, stream>>>(enc_w1, enc_b1, enc_w2, hi_w0, hi_w1,
                                                wih0, whh0, wih1, whh1, mu_w, lv_w,
                                                mu_b, lv_b, pk, bpq);
    xcvt<<<2500, blk, 0, stream>>>(x, xbf);
    hipMemsetAsync(agg, 0, (size_t)N_NODES * 256 * sizeof(float), stream);

    // dst-sort the edges (counting sort)
    hipMemsetAsync(cnt, 0, N_NODES * sizeof(int), stream);
    hist_dst<<<(N_EDGES + 255) / 256, blk, 0, stream>>>(ei, cnt);
    scan_hist<<<1, blk, 0, stream>>>(cnt, rcur);
    scatter_edges<<<(N_EDGES + 255) / 256, blk, 0, stream>>>(ei, rcur, ssrc, sdst);

    // PQ = xbf @ WPQ^T + bPQ -> bf16 [N,512]
    mgemm<128, 1><<<dim3(313, 4), blk, 0, stream>>>(xbf, 128, N_NODES, 128,
                                                    pk + 0, 32, bpq, nullptr, pqbf, 512);
    // edge layer2 + segment-max on sorted edges
    edge_mfma<<<10000, blk, 0, stream>>>(pqbf, sdst, ssrc, pk + 65536, enc_b2, agg);

    build_feat<<<22500, blk, 0, stream>>>(agg, t, a, featbf);

    // h0, h1 = tanh(feat @ hi_w^T + b)  (dual f32 + bf16)
    mgemm<128, 2><<<dim3(313, 2), blk, 0, stream>>>(featbf, 288, N_NODES, 288,
                                                    pk + 131072, 16, hi_b0, h0f, h0bf, 256);
    mgemm<128, 2><<<dim3(313, 2), blk, 0, stream>>>(featbf, 288, N_NODES, 288,
                                                    pk + 204800, 16, hi_b1, h1f, h1bf, 256);
    // fused GRU layers
    gru_fused<<<dim3(313, 4), blk, 0, stream>>>(featbf, 288, h0bf,
                                                pk + 278528, pk + 499712,
                                                bih0, bhh0, h0f, out_h0, nh0bf);
    gru_fused<<<dim3(313, 4), blk, 0, stream>>>(nh0bf, 256, h1bf,
                                                pk + 696320, pk + 892928,
                                                bih1, bhh1, h1f, out_h1, nh1bf);
    // fused heads: mu | lv | z in one kernel (eps via spare pointer arg)
    mgemm<128, 4><<<dim3(313, 1), blk, 0, stream>>>(nh1bf, 256, N_NODES, 256,
                                                    pk + 1089536, 8, bpq + 512,
                                                    out_mu, (ushort_t*)eps, 64);
}